// Round 1
// baseline (1362.071 us; speedup 1.0000x reference)
//
#include <hip/hip_runtime.h>
#include <cmath>

#define BKK 16

// ---------------------------------------------------------------------------
// Tiled fp32 GEMM: C[M,N] = A[M,K] @ B + bias
//   B_NK=false: B stored (K,N) row-major (normal)
//   B_NK=true : B stored (N,K) row-major (i.e. computes A @ B^T)
// 64x64 tile, BK=16, 256 threads, 4x4 per-thread microtile.
// LDS layout: As[k][m], Bs[k][n], pitch 68 (float4-aligned, <=2-way banks).
// ---------------------------------------------------------------------------
template<bool B_NK, bool HAS_BIAS>
__global__ __launch_bounds__(256) void gemm64(const float* __restrict__ A,
                                              const float* __restrict__ B,
                                              const float* __restrict__ bias,
                                              float* __restrict__ C,
                                              int M, int N, int K)
{
    __shared__ float As[BKK][68];
    __shared__ float Bs[BKK][68];

    const int tid  = threadIdx.x;
    const int tx   = tid & 15;
    const int ty   = tid >> 4;
    const int row0 = blockIdx.y * 64;
    const int col0 = blockIdx.x * 64;

    const int lr  = tid >> 2;          // 0..63: A row (and B_NK col)
    const int lkc = (tid & 3) << 2;    // 0,4,8,12: k sub-offset
    const int bkk = tid >> 4;          // 0..15: B_KN k row
    const int bnc = (tid & 15) << 2;   // 0..60: B_KN col offset

    const float* Aptr = A + (size_t)(row0 + lr) * K + lkc;
    const float* Bptr = B_NK ? (B + (size_t)(col0 + lr) * K + lkc)
                             : (B + (size_t)bkk * N + col0 + bnc);

    float4 av = *(const float4*)(Aptr);
    float4 bv = *(const float4*)(Bptr);

    float acc[4][4] = {};

    for (int k0 = 0; k0 < K; k0 += BKK) {
        __syncthreads();   // previous iteration's LDS reads are done
        As[lkc + 0][lr] = av.x;
        As[lkc + 1][lr] = av.y;
        As[lkc + 2][lr] = av.z;
        As[lkc + 3][lr] = av.w;
        if (B_NK) {
            Bs[lkc + 0][lr] = bv.x;
            Bs[lkc + 1][lr] = bv.y;
            Bs[lkc + 2][lr] = bv.z;
            Bs[lkc + 3][lr] = bv.w;
        } else {
            *(float4*)&Bs[bkk][bnc] = bv;
        }
        __syncthreads();

        // prefetch next tile (wraps to 0 on last iter: harmless reload)
        const int k0n = (k0 + BKK < K) ? (k0 + BKK) : 0;
        av = *(const float4*)(Aptr + k0n);
        bv = B_NK ? *(const float4*)(Bptr + k0n)
                  : *(const float4*)(Bptr + (size_t)k0n * N);

        #pragma unroll
        for (int kk = 0; kk < BKK; ++kk) {
            const float4 a4 = *(const float4*)&As[kk][ty << 2];
            const float4 b4 = *(const float4*)&Bs[kk][tx << 2];
            const float a[4] = {a4.x, a4.y, a4.z, a4.w};
            const float b[4] = {b4.x, b4.y, b4.z, b4.w};
            #pragma unroll
            for (int i = 0; i < 4; ++i)
                #pragma unroll
                for (int j = 0; j < 4; ++j)
                    acc[i][j] = fmaf(a[i], b[j], acc[i][j]);
        }
    }

    float bb[4] = {0.f, 0.f, 0.f, 0.f};
    if (HAS_BIAS) {
        #pragma unroll
        for (int j = 0; j < 4; ++j) bb[j] = bias[col0 + (tx << 2) + j];
    }
    #pragma unroll
    for (int i = 0; i < 4; ++i) {
        float4 o;
        o.x = acc[i][0] + bb[0];
        o.y = acc[i][1] + bb[1];
        o.z = acc[i][2] + bb[2];
        o.w = acc[i][3] + bb[3];
        *(float4*)(C + (size_t)(row0 + (ty << 2) + i) * N + col0 + (tx << 2)) = o;
    }
}

// ---------------------------------------------------------------------------
// Flash-style attention. One block = (b, h, 64-query tile). fp32 throughout.
//   q: q_latent (B*S, 512), head h cols [h*32, h*32+32)
//   k: combined (B*S, 512), same head slice
//   v: v_full   (B*S, 1024), head h cols [h*64, h*64+64)
//   z out:      (B*S, 1024), head h cols [h*64, h*64+64)
// Mask term computed with __fmul_rn/__fadd_rn to match XLA's separate
// mul/add rounding (winner selection at |t|~1e9, ulp=64, must bit-match).
// ---------------------------------------------------------------------------
__global__ __launch_bounds__(256) void attn64(const float* __restrict__ ql,
                                              const float* __restrict__ kl,
                                              const float* __restrict__ vf,
                                              const float* __restrict__ mask,
                                              float* __restrict__ z)
{
    __shared__ float Qt[32][68];   // Qt[d][row]
    __shared__ float Kt[32][68];   // Kt[d][key]
    __shared__ float Vs[64][64];   // Vs[key][col]
    __shared__ float Ps[64][68];   // Ps[row][key]
    __shared__ float mq_s[64];
    __shared__ float mk_s[64];

    const int tid = threadIdx.x;
    const int tx  = tid & 15;
    const int ty  = tid >> 4;
    const int qt  = blockIdx.x;
    const int h   = blockIdx.y;
    const int b   = blockIdx.z;
    const int s0q = qt << 6;

    const int tr  = tid >> 3;          // 0..31
    const int tdc = (tid & 7) << 2;    // 0..28
    const int vr  = tid >> 4;          // 0..15
    const int vc  = (tid & 15) << 2;   // 0..60

    // load Q transposed + query mask
    #pragma unroll
    for (int p = 0; p < 2; ++p) {
        const int r = tr + (p << 5);
        const float4 qv = *(const float4*)(ql + (size_t)(b * 1024 + s0q + r) * 512 + (h << 5) + tdc);
        Qt[tdc + 0][r] = qv.x;
        Qt[tdc + 1][r] = qv.y;
        Qt[tdc + 2][r] = qv.z;
        Qt[tdc + 3][r] = qv.w;
    }
    if (tid < 64) mq_s[tid] = mask[b * 1024 + s0q + tid];

    float m_run[4], l_run[4], acc_o[4][4];
    #pragma unroll
    for (int i = 0; i < 4; ++i) {
        m_run[i] = -INFINITY;
        l_run[i] = 0.f;
        #pragma unroll
        for (int j = 0; j < 4; ++j) acc_o[i][j] = 0.f;
    }

    const float scale = 0.17677669529663687f;   // 1/sqrt(32)

    // prefetch key-tile 0
    float4 kreg[2], vreg[4];
    float  mreg;
    #pragma unroll
    for (int p = 0; p < 2; ++p)
        kreg[p] = *(const float4*)(kl + (size_t)(b * 1024 + tr + (p << 5)) * 512 + (h << 5) + tdc);
    #pragma unroll
    for (int p = 0; p < 4; ++p)
        vreg[p] = *(const float4*)(vf + (size_t)(b * 1024 + vr + (p << 4)) * 1024 + (h << 6) + vc);
    mreg = (tid < 64) ? mask[b * 1024 + tid] : 0.f;

    for (int kt = 0; kt < 16; ++kt) {
        __syncthreads();   // prior tile's LDS reads complete
        #pragma unroll
        for (int p = 0; p < 2; ++p) {
            const int r = tr + (p << 5);
            Kt[tdc + 0][r] = kreg[p].x;
            Kt[tdc + 1][r] = kreg[p].y;
            Kt[tdc + 2][r] = kreg[p].z;
            Kt[tdc + 3][r] = kreg[p].w;
        }
        #pragma unroll
        for (int p = 0; p < 4; ++p)
            *(float4*)&Vs[vr + (p << 4)][vc] = vreg[p];
        if (tid < 64) mk_s[tid] = mreg;
        __syncthreads();

        // prefetch next tile (wraps; redundant last load is harmless)
        {
            const int s0k = ((kt + 1) & 15) << 6;
            #pragma unroll
            for (int p = 0; p < 2; ++p)
                kreg[p] = *(const float4*)(kl + (size_t)(b * 1024 + s0k + tr + (p << 5)) * 512 + (h << 5) + tdc);
            #pragma unroll
            for (int p = 0; p < 4; ++p)
                vreg[p] = *(const float4*)(vf + (size_t)(b * 1024 + s0k + vr + (p << 4)) * 1024 + (h << 6) + vc);
            mreg = (tid < 64) ? mask[b * 1024 + s0k + tid] : 0.f;
        }

        // scores: outer product over d=32
        float sc[4][4] = {};
        #pragma unroll
        for (int kk = 0; kk < 32; ++kk) {
            const float4 a4 = *(const float4*)&Qt[kk][ty << 2];
            const float4 b4 = *(const float4*)&Kt[kk][tx << 2];
            const float a[4]  = {a4.x, a4.y, a4.z, a4.w};
            const float bb[4] = {b4.x, b4.y, b4.z, b4.w};
            #pragma unroll
            for (int i = 0; i < 4; ++i)
                #pragma unroll
                for (int j = 0; j < 4; ++j)
                    sc[i][j] = fmaf(a[i], bb[j], sc[i][j]);
        }

        float mkv[4];
        #pragma unroll
        for (int j = 0; j < 4; ++j) mkv[j] = mk_s[(tx << 2) + j];

        // mask + online softmax (rows ty*4+i span lanes tx=0..15, same wave)
        float p[4][4];
        #pragma unroll
        for (int i = 0; i < 4; ++i) {
            const float mq = mq_s[(ty << 2) + i];
            float mx = -INFINITY;
            #pragma unroll
            for (int j = 0; j < 4; ++j) {
                const float m2 = fminf(1.f, __fadd_rn(mq, mkv[j]));
                const float t  = __fmul_rn(m2, -1.0e9f);
                const float v  = __fadd_rn(__fmul_rn(sc[i][j], scale), t);
                sc[i][j] = v;
                mx = fmaxf(mx, v);
            }
            #pragma unroll
            for (int off = 8; off >= 1; off >>= 1)
                mx = fmaxf(mx, __shfl_xor(mx, off));
            const float m_new = fmaxf(m_run[i], mx);
            const float alpha = __expf(m_run[i] - m_new);   // exp(-inf)=0 first iter
            float sum = 0.f;
            #pragma unroll
            for (int j = 0; j < 4; ++j) {
                const float e = __expf(sc[i][j] - m_new);
                p[i][j] = e;
                sum += e;
            }
            #pragma unroll
            for (int off = 8; off >= 1; off >>= 1)
                sum += __shfl_xor(sum, off);
            l_run[i] = l_run[i] * alpha + sum;
            m_run[i] = m_new;
            #pragma unroll
            for (int j = 0; j < 4; ++j) acc_o[i][j] *= alpha;
        }

        // stage P, then PV outer product over 64 keys
        #pragma unroll
        for (int i = 0; i < 4; ++i)
            *(float4*)&Ps[(ty << 2) + i][tx << 2] = make_float4(p[i][0], p[i][1], p[i][2], p[i][3]);
        __syncthreads();

        #pragma unroll
        for (int kk = 0; kk < 64; ++kk) {
            const float4 v4 = *(const float4*)&Vs[kk][tx << 2];
            #pragma unroll
            for (int i = 0; i < 4; ++i) {
                const float pp = Ps[(ty << 2) + i][kk];
                acc_o[i][0] = fmaf(pp, v4.x, acc_o[i][0]);
                acc_o[i][1] = fmaf(pp, v4.y, acc_o[i][1]);
                acc_o[i][2] = fmaf(pp, v4.z, acc_o[i][2]);
                acc_o[i][3] = fmaf(pp, v4.w, acc_o[i][3]);
            }
        }
    }

    #pragma unroll
    for (int i = 0; i < 4; ++i) {
        const float inv = 1.f / l_run[i];
        float4 o;
        o.x = acc_o[i][0] * inv;
        o.y = acc_o[i][1] * inv;
        o.z = acc_o[i][2] * inv;
        o.w = acc_o[i][3] * inv;
        *(float4*)(z + (size_t)(b * 1024 + s0q + (ty << 2) + i) * 1024 + (h << 6) + (tx << 2)) = o;
    }
}

// ---------------------------------------------------------------------------
extern "C" void kernel_launch(void* const* d_in, const int* in_sizes, int n_in,
                              void* d_out, int out_size, void* d_ws, size_t ws_size,
                              hipStream_t stream)
{
    const float* x     = (const float*)d_in[0];
    const float* mask  = (const float*)d_in[1];
    const float* wq    = (const float*)d_in[2];
    const float* bq    = (const float*)d_in[3];
    const float* w_ckv = (const float*)d_in[4];
    const float* wuk   = (const float*)d_in[5];
    const float* wuv   = (const float*)d_in[6];
    const float* wo    = (const float*)d_in[7];
    const float* bo    = (const float*)d_in[8];
    float* out = (float*)d_out;

    // workspace layout (96 MB): q_full region reused for z (q_full dead after G2)
    char* ws = (char*)d_ws;
    float* q_full   = (float*)ws;                        // 32 MB
    float* z        = q_full;                            // reuse
    float* q_latent = (float*)(ws + (size_t)(32u << 20)); // 16 MB
    float* combined = (float*)(ws + (size_t)(48u << 20)); // 16 MB
    float* v_full   = (float*)(ws + (size_t)(64u << 20)); // 32 MB

    const dim3 blk(256);
    const int M = 8192;

    // q_full = x @ wq + bq              (8192,1024,K=1024)
    gemm64<false, true ><<<dim3(1024 / 64, M / 64), blk, 0, stream>>>(x,        wq,    bq,      q_full,   M, 1024, 1024);
    // q_latent = q_full @ wuk^T         (8192,512, K=1024), wuk is (512,1024)
    gemm64<true,  false><<<dim3(512  / 64, M / 64), blk, 0, stream>>>(q_full,   wuk,   nullptr, q_latent, M, 512,  1024);
    // combined = x @ w_ckv              (8192,512, K=1024)
    gemm64<false, false><<<dim3(512  / 64, M / 64), blk, 0, stream>>>(x,        w_ckv, nullptr, combined, M, 512,  1024);
    // v_full = combined @ wuv           (8192,1024,K=512)
    gemm64<false, false><<<dim3(1024 / 64, M / 64), blk, 0, stream>>>(combined, wuv,   nullptr, v_full,   M, 1024, 512);
    // attention -> z
    attn64<<<dim3(16, 16, 8), blk, 0, stream>>>(q_latent, combined, v_full, mask, z);
    // out = z @ wo + bo                 (8192,1024,K=1024)
    gemm64<false, true ><<<dim3(1024 / 64, M / 64), blk, 0, stream>>>(z,        wo,    bo,      out,      M, 1024, 1024);
}

// Round 2
// 645.074 us; speedup vs baseline: 2.1115x; 2.1115x over previous
//
#include <hip/hip_runtime.h>
#include <cmath>

typedef __attribute__((ext_vector_type(8))) short bf16x8;
typedef __attribute__((ext_vector_type(4))) float f32x4;

__device__ __forceinline__ float bf2f(ushort u) {
    union { unsigned int u; float f; } c;
    c.u = ((unsigned int)u) << 16;
    return c.f;
}
__device__ __forceinline__ ushort f2bf(float f) {
    union { float f; unsigned int u; } c;
    c.f = f;
    unsigned int lsb = (c.u >> 16) & 1u;
    return (ushort)((c.u + 0x7fffu + lsb) >> 16);
}

// async global->LDS, 16B per lane. LDS dest = wave-uniform base + lane*16.
__device__ __forceinline__ void gl2lds16(const ushort* g, ushort* l) {
    __builtin_amdgcn_global_load_lds((const __attribute__((address_space(1))) void*)g,
                                     (__attribute__((address_space(3))) void*)l,
                                     16, 0, 0);
}

// ---------------------------------------------------------------------------
// straight cast fp32 -> bf16 (4 elems/thread)
// ---------------------------------------------------------------------------
__global__ __launch_bounds__(256) void cast_bf16(const float* __restrict__ in,
                                                 ushort* __restrict__ out, int n)
{
    int i = (blockIdx.x * 256 + threadIdx.x) * 4;
    if (i < n) {
        const float4 v = *(const float4*)(in + i);
        ushort4 o;
        o.x = f2bf(v.x); o.y = f2bf(v.y); o.z = f2bf(v.z); o.w = f2bf(v.w);
        *(ushort4*)(out + i) = o;
    }
}

// ---------------------------------------------------------------------------
// transpose + cast: in (R,C) fp32 row-major -> out (C,R) bf16 row-major
// ---------------------------------------------------------------------------
__global__ __launch_bounds__(256) void transpose_cast(const float* __restrict__ in,
                                                      ushort* __restrict__ out,
                                                      int R, int C)
{
    __shared__ float t[32][33];
    const int tx = threadIdx.x & 31;
    const int ty = threadIdx.x >> 5;      // 0..7
    const int r0 = blockIdx.y << 5;
    const int c0 = blockIdx.x << 5;
    #pragma unroll
    for (int i = ty; i < 32; i += 8)
        t[i][tx] = in[(size_t)(r0 + i) * C + c0 + tx];
    __syncthreads();
    #pragma unroll
    for (int i = ty; i < 32; i += 8)
        out[(size_t)(c0 + i) * R + r0 + tx] = f2bf(t[tx][i]);
}

// ---------------------------------------------------------------------------
// bf16 MFMA GEMM: C[M,N] = A[M,K] @ Bt[N,K]^T (+bias)
// 128x128x32 tile, 256 threads = 4 waves (2x2), each wave 4x4 of 16x16x32.
// m97 structure: global_load_lds width-16 staging, 2 barriers / K-tile.
// ---------------------------------------------------------------------------
template<bool OUT_F32, bool HAS_BIAS>
__global__ __launch_bounds__(256) void gemm_bt(const ushort* __restrict__ A,
                                               const ushort* __restrict__ Bt,
                                               const float* __restrict__ bias,
                                               void* __restrict__ Cv,
                                               int M, int N, int K)
{
    __shared__ ushort As[128 * 32];
    __shared__ ushort Bs[128 * 32];

    const int tid  = threadIdx.x;
    const int wave = tid >> 6;
    const int lane = tid & 63;
    const int row0 = blockIdx.y << 7;
    const int col0 = blockIdx.x << 7;

    // staging: each global_load_lds call = 64 lanes x 16B = 16 rows x 32 bf16
    const int srow = lane >> 2;          // 0..15
    const int skc  = (lane & 3) << 3;    // 0,8,16,24 (elements)
    const ushort* Ag0 = A  + (size_t)(row0 + wave * 32 +      srow) * K + skc;
    const ushort* Ag1 = A  + (size_t)(row0 + wave * 32 + 16 + srow) * K + skc;
    const ushort* Bg0 = Bt + (size_t)(col0 + wave * 32 +      srow) * K + skc;
    const ushort* Bg1 = Bt + (size_t)(col0 + wave * 32 + 16 + srow) * K + skc;
    ushort* Asl0 = &As[(wave * 2 + 0) * 512];
    ushort* Asl1 = &As[(wave * 2 + 1) * 512];
    ushort* Bsl0 = &Bs[(wave * 2 + 0) * 512];
    ushort* Bsl1 = &Bs[(wave * 2 + 1) * 512];

    // compute-phase fragment addressing
    const int wr = (wave >> 1) << 6;     // 0 or 64
    const int wc = (wave & 1) << 6;
    const int ln = lane & 15;
    const int hi = lane >> 4;            // 0..3
    const int a_off = (wr + ln) * 32 + hi * 8;   // elements
    const int b_off = (wc + ln) * 32 + hi * 8;

    f32x4 acc[4][4];
    #pragma unroll
    for (int i = 0; i < 4; ++i)
        #pragma unroll
        for (int j = 0; j < 4; ++j)
            acc[i][j] = (f32x4){0.f, 0.f, 0.f, 0.f};

    for (int k0 = 0; k0 < K; k0 += 32) {
        __syncthreads();                 // prior iter's LDS reads done
        gl2lds16(Ag0 + k0, Asl0);
        gl2lds16(Ag1 + k0, Asl1);
        gl2lds16(Bg0 + k0, Bsl0);
        gl2lds16(Bg1 + k0, Bsl1);
        __syncthreads();                 // compiler drains vmcnt before barrier

        bf16x8 a[4], b[4];
        #pragma unroll
        for (int i = 0; i < 4; ++i) a[i] = *(const bf16x8*)&As[a_off + i * 512];
        #pragma unroll
        for (int j = 0; j < 4; ++j) b[j] = *(const bf16x8*)&Bs[b_off + j * 512];
        #pragma unroll
        for (int i = 0; i < 4; ++i)
            #pragma unroll
            for (int j = 0; j < 4; ++j)
                acc[i][j] = __builtin_amdgcn_mfma_f32_16x16x32_bf16(a[i], b[j], acc[i][j], 0, 0, 0);
    }

    // epilogue: C/D map col=lane&15, row=(lane>>4)*4+reg  [m89/m91]
    #pragma unroll
    for (int j = 0; j < 4; ++j) {
        const int col = col0 + wc + (j << 4) + ln;
        const float bb = HAS_BIAS ? bias[col] : 0.f;
        #pragma unroll
        for (int i = 0; i < 4; ++i) {
            const int rbase = row0 + wr + (i << 4) + (hi << 2);
            #pragma unroll
            for (int r = 0; r < 4; ++r) {
                const float v = acc[i][j][r] + bb;
                if (OUT_F32) ((float*)Cv)[(size_t)(rbase + r) * N + col] = v;
                else         ((ushort*)Cv)[(size_t)(rbase + r) * N + col] = f2bf(v);
            }
        }
    }
}

// ---------------------------------------------------------------------------
// Flash-style attention, bf16 inputs/outputs, fp32 compute in LDS/regs.
// One block = (b, h, 64-query tile).
// Mask arithmetic stays exact fp32 (__fadd_rn/__fmul_rn) -> winner selection
// matches the reference bitwise; bf16 QK scores are erased by 1e9 rounding.
// ---------------------------------------------------------------------------
__global__ __launch_bounds__(256) void attn64(const ushort* __restrict__ ql,
                                              const ushort* __restrict__ kl,
                                              const ushort* __restrict__ vf,
                                              const float* __restrict__ mask,
                                              ushort* __restrict__ z)
{
    __shared__ float Qt[32][68];   // Qt[d][row]
    __shared__ float Kt[32][68];   // Kt[d][key]
    __shared__ float Vs[64][64];   // Vs[key][col]
    __shared__ float Ps[64][68];   // Ps[row][key]
    __shared__ float mq_s[64];
    __shared__ float mk_s[64];

    const int tid = threadIdx.x;
    const int tx  = tid & 15;
    const int ty  = tid >> 4;
    const int qt  = blockIdx.x;
    const int h   = blockIdx.y;
    const int b   = blockIdx.z;
    const int s0q = qt << 6;

    const int tr  = tid >> 3;          // 0..31
    const int tdc = (tid & 7) << 2;    // 0..28
    const int vr  = tid >> 4;          // 0..15
    const int vc  = (tid & 15) << 2;   // 0..60

    #pragma unroll
    for (int p = 0; p < 2; ++p) {
        const int r = tr + (p << 5);
        const ushort4 qv = *(const ushort4*)(ql + (size_t)(b * 1024 + s0q + r) * 512 + (h << 5) + tdc);
        Qt[tdc + 0][r] = bf2f(qv.x);
        Qt[tdc + 1][r] = bf2f(qv.y);
        Qt[tdc + 2][r] = bf2f(qv.z);
        Qt[tdc + 3][r] = bf2f(qv.w);
    }
    if (tid < 64) mq_s[tid] = mask[b * 1024 + s0q + tid];

    float m_run[4], l_run[4], acc_o[4][4];
    #pragma unroll
    for (int i = 0; i < 4; ++i) {
        m_run[i] = -INFINITY;
        l_run[i] = 0.f;
        #pragma unroll
        for (int j = 0; j < 4; ++j) acc_o[i][j] = 0.f;
    }

    const float scale = 0.17677669529663687f;   // 1/sqrt(32)

    ushort4 kreg[2], vreg[4];
    float   mreg;
    #pragma unroll
    for (int p = 0; p < 2; ++p)
        kreg[p] = *(const ushort4*)(kl + (size_t)(b * 1024 + tr + (p << 5)) * 512 + (h << 5) + tdc);
    #pragma unroll
    for (int p = 0; p < 4; ++p)
        vreg[p] = *(const ushort4*)(vf + (size_t)(b * 1024 + vr + (p << 4)) * 1024 + (h << 6) + vc);
    mreg = (tid < 64) ? mask[b * 1024 + tid] : 0.f;

    for (int kt = 0; kt < 16; ++kt) {
        __syncthreads();
        #pragma unroll
        for (int p = 0; p < 2; ++p) {
            const int r = tr + (p << 5);
            Kt[tdc + 0][r] = bf2f(kreg[p].x);
            Kt[tdc + 1][r] = bf2f(kreg[p].y);
            Kt[tdc + 2][r] = bf2f(kreg[p].z);
            Kt[tdc + 3][r] = bf2f(kreg[p].w);
        }
        #pragma unroll
        for (int p = 0; p < 4; ++p) {
            float4 vv;
            vv.x = bf2f(vreg[p].x); vv.y = bf2f(vreg[p].y);
            vv.z = bf2f(vreg[p].z); vv.w = bf2f(vreg[p].w);
            *(float4*)&Vs[vr + (p << 4)][vc] = vv;
        }
        if (tid < 64) mk_s[tid] = mreg;
        __syncthreads();

        {   // prefetch next tile (wraps; harmless)
            const int s0k = ((kt + 1) & 15) << 6;
            #pragma unroll
            for (int p = 0; p < 2; ++p)
                kreg[p] = *(const ushort4*)(kl + (size_t)(b * 1024 + s0k + tr + (p << 5)) * 512 + (h << 5) + tdc);
            #pragma unroll
            for (int p = 0; p < 4; ++p)
                vreg[p] = *(const ushort4*)(vf + (size_t)(b * 1024 + s0k + vr + (p << 4)) * 1024 + (h << 6) + vc);
            mreg = (tid < 64) ? mask[b * 1024 + s0k + tid] : 0.f;
        }

        float sc[4][4] = {};
        #pragma unroll
        for (int kk = 0; kk < 32; ++kk) {
            const float4 a4 = *(const float4*)&Qt[kk][ty << 2];
            const float4 b4 = *(const float4*)&Kt[kk][tx << 2];
            const float a[4]  = {a4.x, a4.y, a4.z, a4.w};
            const float bb[4] = {b4.x, b4.y, b4.z, b4.w};
            #pragma unroll
            for (int i = 0; i < 4; ++i)
                #pragma unroll
                for (int j = 0; j < 4; ++j)
                    sc[i][j] = fmaf(a[i], bb[j], sc[i][j]);
        }

        float mkv[4];
        #pragma unroll
        for (int j = 0; j < 4; ++j) mkv[j] = mk_s[(tx << 2) + j];

        float p[4][4];
        #pragma unroll
        for (int i = 0; i < 4; ++i) {
            const float mq = mq_s[(ty << 2) + i];
            float mx = -INFINITY;
            #pragma unroll
            for (int j = 0; j < 4; ++j) {
                const float m2 = fminf(1.f, __fadd_rn(mq, mkv[j]));
                const float t  = __fmul_rn(m2, -1.0e9f);
                const float v  = __fadd_rn(__fmul_rn(sc[i][j], scale), t);
                sc[i][j] = v;
                mx = fmaxf(mx, v);
            }
            #pragma unroll
            for (int off = 8; off >= 1; off >>= 1)
                mx = fmaxf(mx, __shfl_xor(mx, off));
            const float m_new = fmaxf(m_run[i], mx);
            const float alpha = __expf(m_run[i] - m_new);
            float sum = 0.f;
            #pragma unroll
            for (int j = 0; j < 4; ++j) {
                const float e = __expf(sc[i][j] - m_new);
                p[i][j] = e;
                sum += e;
            }
            #pragma unroll
            for (int off = 8; off >= 1; off >>= 1)
                sum += __shfl_xor(sum, off);
            l_run[i] = l_run[i] * alpha + sum;
            m_run[i] = m_new;
            #pragma unroll
            for (int j = 0; j < 4; ++j) acc_o[i][j] *= alpha;
        }

        #pragma unroll
        for (int i = 0; i < 4; ++i)
            *(float4*)&Ps[(ty << 2) + i][tx << 2] = make_float4(p[i][0], p[i][1], p[i][2], p[i][3]);
        __syncthreads();

        // PV: b128 Ps reads (4-k chunks)
        #pragma unroll
        for (int kk = 0; kk < 64; kk += 4) {
            float4 pv[4];
            #pragma unroll
            for (int i = 0; i < 4; ++i)
                pv[i] = *(const float4*)&Ps[(ty << 2) + i][kk];
            #pragma unroll
            for (int c = 0; c < 4; ++c) {
                const float4 v4 = *(const float4*)&Vs[kk + c][tx << 2];
                #pragma unroll
                for (int i = 0; i < 4; ++i) {
                    const float pp = (c == 0) ? pv[i].x : (c == 1) ? pv[i].y
                                   : (c == 2) ? pv[i].z : pv[i].w;
                    acc_o[i][0] = fmaf(pp, v4.x, acc_o[i][0]);
                    acc_o[i][1] = fmaf(pp, v4.y, acc_o[i][1]);
                    acc_o[i][2] = fmaf(pp, v4.z, acc_o[i][2]);
                    acc_o[i][3] = fmaf(pp, v4.w, acc_o[i][3]);
                }
            }
        }
    }

    #pragma unroll
    for (int i = 0; i < 4; ++i) {
        const float inv = 1.f / l_run[i];
        ushort4 o;
        o.x = f2bf(acc_o[i][0] * inv);
        o.y = f2bf(acc_o[i][1] * inv);
        o.z = f2bf(acc_o[i][2] * inv);
        o.w = f2bf(acc_o[i][3] * inv);
        *(ushort4*)(z + (size_t)(b * 1024 + s0q + (ty << 2) + i) * 1024 + (h << 6) + (tx << 2)) = o;
    }
}

// ---------------------------------------------------------------------------
extern "C" void kernel_launch(void* const* d_in, const int* in_sizes, int n_in,
                              void* d_out, int out_size, void* d_ws, size_t ws_size,
                              hipStream_t stream)
{
    const float* x     = (const float*)d_in[0];
    const float* mask  = (const float*)d_in[1];
    const float* wq    = (const float*)d_in[2];
    const float* bq    = (const float*)d_in[3];
    const float* w_ckv = (const float*)d_in[4];
    const float* wuk   = (const float*)d_in[5];
    const float* wuv   = (const float*)d_in[6];
    const float* wo    = (const float*)d_in[7];
    const float* bo    = (const float*)d_in[8];
    float* out = (float*)d_out;

    // workspace (bf16 buffers), offsets in MB
    char* ws = (char*)d_ws;
    ushort* x_bf     = (ushort*)(ws);                         // 16 MB
    ushort* q_full   = (ushort*)(ws + (size_t)(16u << 20));   // 16 MB
    ushort* q_latent = (ushort*)(ws + (size_t)(32u << 20));   //  8 MB
    ushort* combined = (ushort*)(ws + (size_t)(40u << 20));   //  8 MB
    ushort* v_full   = (ushort*)(ws + (size_t)(48u << 20));   // 16 MB
    ushort* z        = (ushort*)(ws + (size_t)(64u << 20));   // 16 MB
    ushort* wq_t     = (ushort*)(ws + (size_t)(80u << 20));   //  2 MB
    ushort* wuk_bf   = (ushort*)(ws + (size_t)(82u << 20));   //  1 MB
    ushort* wckv_t   = (ushort*)(ws + (size_t)(83u << 20));   //  1 MB
    ushort* wuv_t    = (ushort*)(ws + (size_t)(84u << 20));   //  1 MB
    ushort* wo_t     = (ushort*)(ws + (size_t)(85u << 20));   //  2 MB

    const dim3 blk(256);
    const int M = 8192;

    // casts / transposes (weights -> (N,K) bf16)
    cast_bf16<<<dim3(8192 * 1024 / 1024), blk, 0, stream>>>(x, x_bf, 8192 * 1024);
    cast_bf16<<<dim3(512 * 1024 / 1024),  blk, 0, stream>>>(wuk, wuk_bf, 512 * 1024);
    transpose_cast<<<dim3(32, 32), blk, 0, stream>>>(wq,    wq_t,   1024, 1024);
    transpose_cast<<<dim3(16, 32), blk, 0, stream>>>(w_ckv, wckv_t, 1024, 512);
    transpose_cast<<<dim3(32, 16), blk, 0, stream>>>(wuv,   wuv_t,  512,  1024);
    transpose_cast<<<dim3(32, 32), blk, 0, stream>>>(wo,    wo_t,   1024, 1024);

    // GEMM chain (all A[M,K] @ Bt[N,K]^T)
    gemm_bt<false, true ><<<dim3(1024 / 128, M / 128), blk, 0, stream>>>(x_bf,     wq_t,   bq,      q_full,   M, 1024, 1024);
    gemm_bt<false, false><<<dim3(512  / 128, M / 128), blk, 0, stream>>>(q_full,   wuk_bf, nullptr, q_latent, M, 512,  1024);
    gemm_bt<false, false><<<dim3(512  / 128, M / 128), blk, 0, stream>>>(x_bf,     wckv_t, nullptr, combined, M, 512,  1024);
    gemm_bt<false, false><<<dim3(1024 / 128, M / 128), blk, 0, stream>>>(combined, wuv_t,  nullptr, v_full,   M, 1024, 512);

    attn64<<<dim3(16, 16, 8), blk, 0, stream>>>(q_latent, combined, v_full, mask, z);

    gemm_bt<true,  true ><<<dim3(1024 / 128, M / 128), blk, 0, stream>>>(z,        wo_t,   bo,      out,      M, 1024, 1024);
}

// Round 3
// 396.082 us; speedup vs baseline: 3.4389x; 1.6286x over previous
//
#include <hip/hip_runtime.h>
#include <cmath>

typedef __attribute__((ext_vector_type(8))) short bf16x8;
typedef __attribute__((ext_vector_type(4))) short bf16x4;
typedef __attribute__((ext_vector_type(4))) float f32x4;

__device__ __forceinline__ float bf2f(ushort u) {
    union { unsigned int u; float f; } c;
    c.u = ((unsigned int)u) << 16;
    return c.f;
}
__device__ __forceinline__ ushort f2bf(float f) {
    union { float f; unsigned int u; } c;
    c.f = f;
    unsigned int lsb = (c.u >> 16) & 1u;
    return (ushort)((c.u + 0x7fffu + lsb) >> 16);
}

// 8-bf16 LDS load from an 8B-aligned (not necessarily 16B) address
__device__ __forceinline__ bf16x8 lds_ld8(const ushort* p) {
    const bf16x4 lo = *(const bf16x4*)p;
    const bf16x4 hi = *(const bf16x4*)(p + 4);
    bf16x8 r;
    r[0] = lo[0]; r[1] = lo[1]; r[2] = lo[2]; r[3] = lo[3];
    r[4] = hi[0]; r[5] = hi[1]; r[6] = hi[2]; r[7] = hi[3];
    return r;
}

// async global->LDS, 16B per lane. LDS dest = wave-uniform base + lane*16.
__device__ __forceinline__ void gl2lds16(const ushort* g, ushort* l) {
    __builtin_amdgcn_global_load_lds((const __attribute__((address_space(1))) void*)g,
                                     (__attribute__((address_space(3))) void*)l,
                                     16, 0, 0);
}

// ---------------------------------------------------------------------------
__global__ __launch_bounds__(256) void cast_bf16(const float* __restrict__ in,
                                                 ushort* __restrict__ out, int n)
{
    int i = (blockIdx.x * 256 + threadIdx.x) * 4;
    if (i < n) {
        const float4 v = *(const float4*)(in + i);
        ushort4 o;
        o.x = f2bf(v.x); o.y = f2bf(v.y); o.z = f2bf(v.z); o.w = f2bf(v.w);
        *(ushort4*)(out + i) = o;
    }
}

// transpose + cast: in (R,C) fp32 row-major -> out (C,R) bf16 row-major
__global__ __launch_bounds__(256) void transpose_cast(const float* __restrict__ in,
                                                      ushort* __restrict__ out,
                                                      int R, int C)
{
    __shared__ float t[32][33];
    const int tx = threadIdx.x & 31;
    const int ty = threadIdx.x >> 5;
    const int r0 = blockIdx.y << 5;
    const int c0 = blockIdx.x << 5;
    #pragma unroll
    for (int i = ty; i < 32; i += 8)
        t[i][tx] = in[(size_t)(r0 + i) * C + c0 + tx];
    __syncthreads();
    #pragma unroll
    for (int i = ty; i < 32; i += 8)
        out[(size_t)(c0 + i) * R + r0 + tx] = f2bf(t[tx][i]);
}

// b_lat[n] = sum_o bq[o] * wuk[n][o]   (fp32, n in 0..511)
__global__ __launch_bounds__(256) void bias_fold(const float* __restrict__ bq,
                                                 const float* __restrict__ wuk,
                                                 float* __restrict__ b_lat)
{
    const int n = blockIdx.x * 256 + threadIdx.x;
    float s = 0.f;
    for (int o = 0; o < 1024; o += 4) {
        const float4 w = *(const float4*)(wuk + (size_t)n * 1024 + o);
        const float4 q = *(const float4*)(bq + o);
        s = fmaf(q.x, w.x, s); s = fmaf(q.y, w.y, s);
        s = fmaf(q.z, w.z, s); s = fmaf(q.w, w.w, s);
    }
    b_lat[n] = s;
}

// ---------------------------------------------------------------------------
// bf16 MFMA GEMM: C[M,N] = A[M,K] @ Bt[N,K]^T (+bias)
// 128x128x32 tile, 256 threads = 4 waves (2x2), each wave 4x4 of 16x16x32.
// ---------------------------------------------------------------------------
template<bool OUT_F32, bool HAS_BIAS>
__global__ __launch_bounds__(256) void gemm_bt(const ushort* __restrict__ A,
                                               const ushort* __restrict__ Bt,
                                               const float* __restrict__ bias,
                                               void* __restrict__ Cv,
                                               int M, int N, int K)
{
    __shared__ ushort As[128 * 32];
    __shared__ ushort Bs[128 * 32];

    const int tid  = threadIdx.x;
    const int wave = tid >> 6;
    const int lane = tid & 63;
    const int row0 = blockIdx.y << 7;
    const int col0 = blockIdx.x << 7;

    const int srow = lane >> 2;
    const int skc  = (lane & 3) << 3;
    const ushort* Ag0 = A  + (size_t)(row0 + wave * 32 +      srow) * K + skc;
    const ushort* Ag1 = A  + (size_t)(row0 + wave * 32 + 16 + srow) * K + skc;
    const ushort* Bg0 = Bt + (size_t)(col0 + wave * 32 +      srow) * K + skc;
    const ushort* Bg1 = Bt + (size_t)(col0 + wave * 32 + 16 + srow) * K + skc;
    ushort* Asl0 = &As[(wave * 2 + 0) * 512];
    ushort* Asl1 = &As[(wave * 2 + 1) * 512];
    ushort* Bsl0 = &Bs[(wave * 2 + 0) * 512];
    ushort* Bsl1 = &Bs[(wave * 2 + 1) * 512];

    const int wr = (wave >> 1) << 6;
    const int wc = (wave & 1) << 6;
    const int ln = lane & 15;
    const int hi = lane >> 4;
    const int a_off = (wr + ln) * 32 + hi * 8;
    const int b_off = (wc + ln) * 32 + hi * 8;

    f32x4 acc[4][4];
    #pragma unroll
    for (int i = 0; i < 4; ++i)
        #pragma unroll
        for (int j = 0; j < 4; ++j)
            acc[i][j] = (f32x4){0.f, 0.f, 0.f, 0.f};

    for (int k0 = 0; k0 < K; k0 += 32) {
        __syncthreads();
        gl2lds16(Ag0 + k0, Asl0);
        gl2lds16(Ag1 + k0, Asl1);
        gl2lds16(Bg0 + k0, Bsl0);
        gl2lds16(Bg1 + k0, Bsl1);
        __syncthreads();

        bf16x8 a[4], b[4];
        #pragma unroll
        for (int i = 0; i < 4; ++i) a[i] = *(const bf16x8*)&As[a_off + i * 512];
        #pragma unroll
        for (int j = 0; j < 4; ++j) b[j] = *(const bf16x8*)&Bs[b_off + j * 512];
        #pragma unroll
        for (int i = 0; i < 4; ++i)
            #pragma unroll
            for (int j = 0; j < 4; ++j)
                acc[i][j] = __builtin_amdgcn_mfma_f32_16x16x32_bf16(a[i], b[j], acc[i][j], 0, 0, 0);
    }

    #pragma unroll
    for (int j = 0; j < 4; ++j) {
        const int col = col0 + wc + (j << 4) + ln;
        const float bb = HAS_BIAS ? bias[col] : 0.f;
        #pragma unroll
        for (int i = 0; i < 4; ++i) {
            const int rbase = row0 + wr + (i << 4) + (hi << 2);
            #pragma unroll
            for (int r = 0; r < 4; ++r) {
                const float v = acc[i][j][r] + bb;
                if (OUT_F32) ((float*)Cv)[(size_t)(rbase + r) * N + col] = v;
                else         ((ushort*)Cv)[(size_t)(rbase + r) * N + col] = f2bf(v);
            }
        }
    }
}

// ---------------------------------------------------------------------------
// MFMA flash attention. Block = (b, h, 64-query tile); 4 waves x 16 queries.
// QK^T: one 16x16x32 MFMA per 16q x 16k block (d=32). PV: P->LDS (bf16,
// C-layout -> A-layout round-trip), V^T staged in LDS, 2 MFMAs per 16x16.
// Mask arithmetic stays exact fp32 (__fadd_rn/__fmul_rn) as in round 2.
// ---------------------------------------------------------------------------
__global__ __launch_bounds__(256) void attn_mfma(const ushort* __restrict__ ql,
                                                 const ushort* __restrict__ kl,
                                                 const ushort* __restrict__ vf,
                                                 const float* __restrict__ mask,
                                                 ushort* __restrict__ z)
{
    __shared__ ushort Vt[64][68];        // V^T tile: [vcol][key]
    __shared__ ushort Ps[4][16][68];     // per-wave P: [wave][q][key]
    __shared__ float  mk_s[64];

    const int tid  = threadIdx.x;
    const int wave = tid >> 6;
    const int lane = tid & 63;
    const int ln   = lane & 15;
    const int hi   = lane >> 4;
    const int qt = blockIdx.x, h = blockIdx.y, b = blockIdx.z;
    const int s0q = qt << 6;

    // Q A-frag: query = s0q + 16*wave + ln, dims hi*8..+7 (one frag covers d=32)
    const bf16x8 aq = *(const bf16x8*)(ql + (size_t)(b * 1024 + s0q + wave * 16 + ln) * 512 + h * 32 + hi * 8);

    // exact fp32 query-mask for this lane's 4 C-layout rows
    float mqv[4];
    #pragma unroll
    for (int r = 0; r < 4; ++r)
        mqv[r] = mask[b * 1024 + s0q + wave * 16 + hi * 4 + r];

    const int vkey = tid & 63;
    const int vch  = (tid >> 6) << 3;    // 0,8,16,24

    f32x4 acc_o[4];
    #pragma unroll
    for (int jo = 0; jo < 4; ++jo) acc_o[jo] = (f32x4){0.f, 0.f, 0.f, 0.f};
    float m_run[4] = {-INFINITY, -INFINITY, -INFINITY, -INFINITY};
    float l_run[4] = {0.f, 0.f, 0.f, 0.f};

    const float scale = 0.17677669529663687f;   // 1/sqrt(32)

    for (int kt = 0; kt < 16; ++kt) {
        const int s0k = kt << 6;

        __syncthreads();   // prior tile's Vt/mk_s readers done
        {   // stage V^T (each thread: 2x 16B loads, 16 transposed u16 writes)
            const ushort* vrow = vf + (size_t)(b * 1024 + s0k + vkey) * 1024 + h * 64;
            const bf16x8 v0 = *(const bf16x8*)(vrow + vch);
            const bf16x8 v1 = *(const bf16x8*)(vrow + vch + 32);
            #pragma unroll
            for (int j = 0; j < 8; ++j) {
                Vt[vch + j][vkey]      = (ushort)v0[j];
                Vt[vch + 32 + j][vkey] = (ushort)v1[j];
            }
            if (tid < 64) mk_s[tid] = mask[b * 1024 + s0k + tid];
        }
        __syncthreads();

        // K B-frags (direct global; L1/L2-resident) + QK MFMAs
        bf16x8 bk[4];
        #pragma unroll
        for (int j = 0; j < 4; ++j)
            bk[j] = *(const bf16x8*)(kl + (size_t)(b * 1024 + s0k + j * 16 + ln) * 512 + h * 32 + hi * 8);
        f32x4 accS[4];
        #pragma unroll
        for (int j = 0; j < 4; ++j)
            accS[j] = __builtin_amdgcn_mfma_f32_16x16x32_bf16(aq, bk[j], (f32x4){0.f, 0.f, 0.f, 0.f}, 0, 0, 0);

        float mkv[4];
        #pragma unroll
        for (int j = 0; j < 4; ++j) mkv[j] = mk_s[j * 16 + ln];

        // online softmax per C-layout row (row = hi*4+r, col = j*16+ln)
        float pj[4][4];
        #pragma unroll
        for (int r = 0; r < 4; ++r) {
            float v[4];
            float mx = -INFINITY;
            #pragma unroll
            for (int j = 0; j < 4; ++j) {
                const float m2 = fminf(1.f, __fadd_rn(mqv[r], mkv[j]));
                const float t  = __fmul_rn(m2, -1.0e9f);
                v[j] = __fadd_rn(__fmul_rn(accS[j][r], scale), t);
                mx = fmaxf(mx, v[j]);
            }
            #pragma unroll
            for (int off = 8; off >= 1; off >>= 1)
                mx = fmaxf(mx, __shfl_xor(mx, off));
            const float m_new = fmaxf(m_run[r], mx);
            const float alpha = __expf(m_run[r] - m_new);
            float sum = 0.f;
            #pragma unroll
            for (int j = 0; j < 4; ++j) {
                const float e = __expf(v[j] - m_new);
                pj[r][j] = e;
                sum += e;
            }
            #pragma unroll
            for (int off = 8; off >= 1; off >>= 1)
                sum += __shfl_xor(sum, off);
            l_run[r] = l_run[r] * alpha + sum;
            m_run[r] = m_new;
            #pragma unroll
            for (int jo = 0; jo < 4; ++jo) acc_o[jo][r] *= alpha;
        }

        // P -> per-wave LDS (C-layout write), read back as A-frags (wave-local,
        // no barrier: same-wave DS ordering via lgkmcnt)
        #pragma unroll
        for (int r = 0; r < 4; ++r)
            #pragma unroll
            for (int j = 0; j < 4; ++j)
                Ps[wave][hi * 4 + r][j * 16 + ln] = f2bf(pj[r][j]);

        const bf16x8 pa0 = lds_ld8(&Ps[wave][ln][hi * 8]);
        const bf16x8 pa1 = lds_ld8(&Ps[wave][ln][32 + hi * 8]);

        #pragma unroll
        for (int jo = 0; jo < 4; ++jo) {
            const bf16x8 bv0 = lds_ld8(&Vt[jo * 16 + ln][hi * 8]);
            const bf16x8 bv1 = lds_ld8(&Vt[jo * 16 + ln][32 + hi * 8]);
            acc_o[jo] = __builtin_amdgcn_mfma_f32_16x16x32_bf16(pa0, bv0, acc_o[jo], 0, 0, 0);
            acc_o[jo] = __builtin_amdgcn_mfma_f32_16x16x32_bf16(pa1, bv1, acc_o[jo], 0, 0, 0);
        }
    }

    float invl[4];
    #pragma unroll
    for (int r = 0; r < 4; ++r) invl[r] = 1.f / l_run[r];
    #pragma unroll
    for (int jo = 0; jo < 4; ++jo)
        #pragma unroll
        for (int r = 0; r < 4; ++r)
            z[(size_t)(b * 1024 + s0q + wave * 16 + hi * 4 + r) * 1024 + h * 64 + jo * 16 + ln]
                = f2bf(acc_o[jo][r] * invl[r]);
}

// ---------------------------------------------------------------------------
extern "C" void kernel_launch(void* const* d_in, const int* in_sizes, int n_in,
                              void* d_out, int out_size, void* d_ws, size_t ws_size,
                              hipStream_t stream)
{
    const float* x     = (const float*)d_in[0];
    const float* mask  = (const float*)d_in[1];
    const float* wq    = (const float*)d_in[2];
    const float* bq    = (const float*)d_in[3];
    const float* w_ckv = (const float*)d_in[4];
    const float* wuk   = (const float*)d_in[5];
    const float* wuv   = (const float*)d_in[6];
    const float* wo    = (const float*)d_in[7];
    const float* bo    = (const float*)d_in[8];
    float* out = (float*)d_out;

    char* ws = (char*)d_ws;
    ushort* x_bf     = (ushort*)(ws);                         // 16 MB
    ushort* q_latent = (ushort*)(ws + (size_t)(16u << 20));   //  8 MB
    ushort* combined = (ushort*)(ws + (size_t)(24u << 20));   //  8 MB
    ushort* v_full   = (ushort*)(ws + (size_t)(32u << 20));   // 16 MB
    ushort* z        = (ushort*)(ws + (size_t)(48u << 20));   // 16 MB
    ushort* wq_bf    = (ushort*)(ws + (size_t)(64u << 20));   //  2 MB
    ushort* wuk_bf   = (ushort*)(ws + (size_t)(66u << 20));   //  1 MB
    ushort* wckv_t   = (ushort*)(ws + (size_t)(67u << 20));   //  1 MB
    ushort* wuv_t    = (ushort*)(ws + (size_t)(68u << 20));   //  1 MB
    ushort* wo_t     = (ushort*)(ws + (size_t)(69u << 20));   //  2 MB
    ushort* wqk_t    = (ushort*)(ws + (size_t)(71u << 20));   //  1 MB  (512,1024)
    float*  b_lat    = (float*) (ws + (size_t)(72u << 20));   //  2 KB

    const dim3 blk(256);
    const int M = 8192;

    cast_bf16<<<dim3(8192), blk, 0, stream>>>(x,   x_bf,   8192 * 1024);
    cast_bf16<<<dim3(1024), blk, 0, stream>>>(wq,  wq_bf,  1024 * 1024);
    cast_bf16<<<dim3(512),  blk, 0, stream>>>(wuk, wuk_bf, 512 * 1024);
    transpose_cast<<<dim3(16, 32), blk, 0, stream>>>(w_ckv, wckv_t, 1024, 512);
    transpose_cast<<<dim3(32, 16), blk, 0, stream>>>(wuv,   wuv_t,  512,  1024);
    transpose_cast<<<dim3(32, 32), blk, 0, stream>>>(wo,    wo_t,   1024, 1024);
    bias_fold<<<dim3(2), blk, 0, stream>>>(bq, wuk, b_lat);

    // wqk_t[n][i] = sum_o wuk[n][o] * wq[i][o]   (fused Q-path weight, (512,1024))
    gemm_bt<false, false><<<dim3(1024 / 128, 512 / 128), blk, 0, stream>>>(wuk_bf, wq_bf, nullptr, wqk_t, 512, 1024, 1024);

    // q_latent = x @ wqk_t^T + b_lat            (8192, 512, K=1024)
    gemm_bt<false, true ><<<dim3(512  / 128, M / 128), blk, 0, stream>>>(x_bf,     wqk_t,  b_lat,   q_latent, M, 512,  1024);
    // combined = x @ w_ckv                      (8192, 512, K=1024)
    gemm_bt<false, false><<<dim3(512  / 128, M / 128), blk, 0, stream>>>(x_bf,     wckv_t, nullptr, combined, M, 512,  1024);
    // v_full = combined @ wuv                   (8192, 1024, K=512)
    gemm_bt<false, false><<<dim3(1024 / 128, M / 128), blk, 0, stream>>>(combined, wuv_t,  nullptr, v_full,   M, 1024, 512);

    attn_mfma<<<dim3(16, 16, 8), blk, 0, stream>>>(q_latent, combined, v_full, mask, z);

    // out = z @ wo + bo                         (8192, 1024, K=1024)
    gemm_bt<true,  true ><<<dim3(1024 / 128, M / 128), blk, 0, stream>>>(z,        wo_t,   bo,      out,      M, 1024, 1024);
}